// Round 3
// baseline (148.811 us; speedup 1.0000x reference)
//
#include <hip/hip_runtime.h>
#include <hip/hip_bf16.h>

// Conv 3x3, C_IN=128, C_OUT=256, H=W=256, pad=1, stride=1, batch=1.
// R10: fine-grained 8-phase-style schedule (m201 template discipline).
//   R9 post-mortem: 64-MFMA monolithic clusters serialize the LDS pipe (2304 cyc
//   of ds_read_b128 per half-phase) against the matrix pipe (2482 cyc) -> ~36 us.
//   Now each (khw, ci-half) = 4 sub-phases of 16 MFMA, each {reads -> barrier ->
//   lgkm(0) -> setprio 16xMFMA -> barrier}: reads of sub-phase p execute while the
//   matrix pipe drains p-1's backlog (s_barrier doesn't drain MFMA).
//   B split into 2 ci-half buffers (2x33KB) and staged one half-phase ahead
//   (4 loads/thread, cols 1..256; pad cols 0/257 zeroed once in prologue) ->
//   no exposed B stage. A double-buffered as in R9. Tail vmcnt(0) per half-phase
//   (loads are ~2.3 kcyc old by then -> no stall; keeps counting trivial).
//   LDS 131.6 KB (2x33024 B + 2x32768 B), 1 block/CU, 8 waves of 64co x 128sp.

typedef short bf16x8 __attribute__((ext_vector_type(8)));    // 8 bf16 = 4 VGPRs
typedef float f32x4 __attribute__((ext_vector_type(4)));
typedef unsigned short u16x4 __attribute__((ext_vector_type(4)));
typedef unsigned short u16x8 __attribute__((ext_vector_type(8)));

#define CIN   128
#define COUT  256
#define HH    256
#define WW    256
#define HP    258                 // padded
#define ROWP  (HP * CIN)          // padded row stride in elems = 33024

static __device__ __forceinline__ unsigned short f2bf(float v) {
    __hip_bfloat16 b = __float2bfloat16(v);
    return *reinterpret_cast<unsigned short*>(&b);
}

static __device__ __forceinline__ void gload_lds16(const unsigned short* g, unsigned short* l) {
    __builtin_amdgcn_global_load_lds(
        (const __attribute__((address_space(1))) unsigned int*)g,
        (__attribute__((address_space(3))) unsigned int*)l, 16, 0, 0);
}

// ---------------- dispatch 1: fused prepass (edge zero + wreorder + xpose) -----------
// grid: 1024 blocks x 256 threads -- unchanged, verified
__global__ __launch_bounds__(256) void prep_kernel(const float* __restrict__ x,
                                                   const float* __restrict__ w,
                                                   unsigned short* __restrict__ xb,
                                                   unsigned short* __restrict__ wr) {
    int bid = blockIdx.x;
    int t   = threadIdx.x;

    // (a) edge zeroing: blocks 0..64 cover the 16448 vec8 border tasks
    if (bid < 65) {
        int i = bid * 256 + t;
        if (i < 16448) {
            u16x8 z = {0, 0, 0, 0, 0, 0, 0, 0};
            int off;
            if (i < 8256) {
                int r   = (i >= 4128) ? 1 : 0;
                int rem = i - r * 4128;
                off = (r * 257) * ROWP + rem * 8;
            } else {
                int j   = i - 8256;           // 0..8191
                int col = j >> 12;            // 0 or 1
                int rem = j & 4095;
                int hp  = (rem >> 4) + 1;     // 1..256
                int c8  = rem & 15;
                off = hp * ROWP + (col * 257) * CIN + c8 * 8;
            }
            *(u16x8*)(&xb[off]) = z;
        }
    }

    // (b) weight reorder: blocks 0..127, one thread per (co,ci), coalesced
    if (bid < 128) {
        int p = bid * 256 + t;    // 0..32767 = co*128+ci
        const float* src = w + p * 9;
        #pragma unroll
        for (int khw = 0; khw < 9; ++khw)
            wr[khw * (COUT * CIN) + p] = f2bf(src[khw]);
    }

    // (c) xpose: NCHW fp32 -> padded NHWC bf16, one 64-w tile per block
    int h  = bid >> 2;
    int w0 = (bid & 3) * 64;
    __shared__ unsigned short tile[CIN * 72];   // [ci][w], w padded 64->72

    int wq  = t & 15;          // 16 * float4 = 64 w
    int cib = t >> 4;          // 16 ci per pass
    for (int c0 = 0; c0 < CIN; c0 += 16) {
        int ci = c0 + cib;
        float4 v = *(const float4*)(x + ci * (HH * WW) + h * WW + w0 + wq * 4);
        u16x4 p;
        p.x = f2bf(v.x); p.y = f2bf(v.y); p.z = f2bf(v.z); p.w = f2bf(v.w);
        *(u16x4*)(&tile[ci * 72 + wq * 4]) = p;
    }
    __syncthreads();

    for (int it = 0; it < 4; ++it) {
        int idx = it * 256 + t;       // 0..1023
        int ww_ = idx & 63;           // varies within wave (conflict-free LDS reads)
        int c8  = idx >> 6;           // 0..15, wave-uniform
        u16x8 o;
        #pragma unroll
        for (int j = 0; j < 8; ++j)
            o[j] = tile[(c8 * 8 + j) * 72 + ww_];
        int dst = ((h + 1) * HP + (w0 + ww_ + 1)) * CIN + c8 * 8;
        *(u16x8*)(&xb[dst]) = o;
    }
}

// ---------------- dispatch 2: implicit-GEMM MFMA conv, 4-sub-phase schedule ----------
// block tile 256co x 256sp (one output row h), 8 waves of 64co x 128sp, 1 block/CU.
// Half-phase (khw, ci-half): 4 sub-phases of 16 MFMA. Sub-phase 0 also issues all
// staging for the NEXT half-phase (A half-plane always; B ci-half at row changes).
// Ah[p][row 0..255][ci 0..63]: 16B chunk c of row at slot c^(row&7).
// Bh[p][col 0..257][ci 0..63]: 16B chunk c of col at slot c^(col&7); cols 0/257 zero.
__global__ __launch_bounds__(512, 2) void conv_mfma_kernel(const unsigned short* __restrict__ xb,
                                                           const unsigned short* __restrict__ wr,
                                                           const float* __restrict__ bias,
                                                           float* __restrict__ out) {
    __shared__ unsigned short Bh[2][258 * 64];     // 2 x 33024 B
    __shared__ unsigned short Ah[2][256 * 64];     // 2 x 32768 B ; total 131584 B

    // XCD-chunked bijective swizzle: 256 blocks, 8 XCDs -> 32 consecutive rows per XCD.
    int bid = blockIdx.x;
    int h   = (bid & 7) * 32 + (bid >> 3);     // 0..255, one output row per block

    int t    = threadIdx.x;     // 0..511
    int lane = t & 63;
    int wave = t >> 6;
    int wm   = wave >> 1;       // co quarter (0..3), 64 co each
    int wn   = wave & 1;        // spatial half (0/1), 128 sp each
    int quad = lane >> 4;
    int l16  = lane & 15;

    f32x4 acc[4][8];
    #pragma unroll
    for (int mi = 0; mi < 4; ++mi)
        #pragma unroll
        for (int ni = 0; ni < 8; ++ni)
            acc[mi][ni] = (f32x4){0.f, 0.f, 0.f, 0.f};

    // stage A half-plane (khw_, ci-half half_): 2048 segs of 16B, 4 per thread
    auto stageA = [&](int khw_, int half_) {
        const unsigned short* wsrc = wr + (size_t)khw_ * (COUT * CIN) + half_ * 64;
        unsigned short* dst = Ah[half_];
        #pragma unroll
        for (int it = 0; it < 4; ++it) {
            int seg = it * 512 + t;
            int r   = seg >> 3;
            int s   = seg & 7;
            int c   = s ^ (r & 7);
            gload_lds16(wsrc + r * CIN + c * 8, &dst[seg * 8]);
        }
    };
    // stage B ci-half p of row h+kh_: cols 1..256 -> 2048 segs, 4 per thread
    auto stageB = [&](int kh_, int p) {
        const unsigned short* xrow = xb + (size_t)(h + kh_) * ROWP + p * 64;
        unsigned short* dst = Bh[p];
        #pragma unroll
        for (int it = 0; it < 4; ++it) {
            int seg = it * 512 + t;
            int col = (seg >> 3) + 1;
            int s   = seg & 7;
            int c   = s ^ (col & 7);
            gload_lds16(xrow + col * CIN + c * 8, &dst[col * 64 + s * 8]);
        }
    };

    // prologue: zero pad cols (0,257) of both B buffers; stage Bh0/Bh1 (kh=0) + A idx0
    if (t < 32) {
        int buf = t >> 4, colsel = (t >> 3) & 1, s = t & 7;
        int col = colsel ? 257 : 0;
        u16x8 z = {0, 0, 0, 0, 0, 0, 0, 0};
        *(u16x8*)(&Bh[buf][col * 64 + s * 8]) = z;
    }
    stageB(0, 0);
    stageB(0, 1);
    stageA(0, 0);
    asm volatile("s_waitcnt vmcnt(0) lgkmcnt(0)" ::: "memory");
    __builtin_amdgcn_s_barrier();
    __builtin_amdgcn_sched_barrier(0);

    #pragma unroll 1
    for (int kh = 0; kh < 3; ++kh) {
        #pragma unroll
        for (int kw = 0; kw < 3; ++kw) {
            int khw = kh * 3 + kw;
            #pragma unroll
            for (int half = 0; half < 2; ++half) {
                const unsigned short* Acur = Bh[0]; // placeholder, set below
                Acur = Ah[half];
                const unsigned short* Bcur = Bh[half];
                int a_sw = l16 & 7;                 // row&7 for all af rows

                bf16x8 bfr[8], af0, af1, af2, af3;

                // ======== sub-phase 0: kk=0 (lc=quad), mi 0..1 ========
                {
                    int lc = quad;
                    #pragma unroll
                    for (int ni = 0; ni < 8; ++ni) {
                        int col = wn * 128 + ni * 16 + l16 + kw;
                        bfr[ni] = *(bf16x8*)(&Bcur[col * 64 + (lc ^ (col & 7)) * 8]);
                    }
                    af0 = *(bf16x8*)(&Acur[(wm * 64 +  0 + l16) * 64 + (lc ^ a_sw) * 8]);
                    af1 = *(bf16x8*)(&Acur[(wm * 64 + 16 + l16) * 64 + (lc ^ a_sw) * 8]);
                }
                // staging issues for the NEXT half-phase
                if (half == 0) {
                    if (kw == 0 && kh > 0) stageB(kh, 1);
                    stageA(khw, 1);
                } else {
                    if (kw == 2 && kh < 2) stageB(kh + 1, 0);
                    stageA((khw == 8) ? 0 : khw + 1, 0);
                }
                __builtin_amdgcn_s_barrier();
                asm volatile("s_waitcnt lgkmcnt(0)" ::: "memory");
                __builtin_amdgcn_sched_barrier(0);
                __builtin_amdgcn_s_setprio(1);
                #pragma unroll
                for (int ni = 0; ni < 8; ++ni) {
                    acc[0][ni] = __builtin_amdgcn_mfma_f32_16x16x32_bf16(af0, bfr[ni], acc[0][ni], 0, 0, 0);
                    acc[1][ni] = __builtin_amdgcn_mfma_f32_16x16x32_bf16(af1, bfr[ni], acc[1][ni], 0, 0, 0);
                }
                __builtin_amdgcn_s_setprio(0);
                __builtin_amdgcn_s_barrier();
                __builtin_amdgcn_sched_barrier(0);

                // ======== sub-phase 1: kk=0, mi 2..3 (bfr reused) ========
                {
                    int lc = quad;
                    af2 = *(bf16x8*)(&Acur[(wm * 64 + 32 + l16) * 64 + (lc ^ a_sw) * 8]);
                    af3 = *(bf16x8*)(&Acur[(wm * 64 + 48 + l16) * 64 + (lc ^ a_sw) * 8]);
                }
                __builtin_amdgcn_s_barrier();
                asm volatile("s_waitcnt lgkmcnt(0)" ::: "memory");
                __builtin_amdgcn_sched_barrier(0);
                __builtin_amdgcn_s_setprio(1);
                #pragma unroll
                for (int ni = 0; ni < 8; ++ni) {
                    acc[2][ni] = __builtin_amdgcn_mfma_f32_16x16x32_bf16(af2, bfr[ni], acc[2][ni], 0, 0, 0);
                    acc[3][ni] = __builtin_amdgcn_mfma_f32_16x16x32_bf16(af3, bfr[ni], acc[3][ni], 0, 0, 0);
                }
                __builtin_amdgcn_s_setprio(0);
                __builtin_amdgcn_s_barrier();
                __builtin_amdgcn_sched_barrier(0);

                // ======== sub-phase 2: kk=1 (lc=4+quad), mi 0..1 ========
                {
                    int lc = 4 + quad;
                    #pragma unroll
                    for (int ni = 0; ni < 8; ++ni) {
                        int col = wn * 128 + ni * 16 + l16 + kw;
                        bfr[ni] = *(bf16x8*)(&Bcur[col * 64 + (lc ^ (col & 7)) * 8]);
                    }
                    af0 = *(bf16x8*)(&Acur[(wm * 64 +  0 + l16) * 64 + (lc ^ a_sw) * 8]);
                    af1 = *(bf16x8*)(&Acur[(wm * 64 + 16 + l16) * 64 + (lc ^ a_sw) * 8]);
                }
                __builtin_amdgcn_s_barrier();
                asm volatile("s_waitcnt lgkmcnt(0)" ::: "memory");
                __builtin_amdgcn_sched_barrier(0);
                __builtin_amdgcn_s_setprio(1);
                #pragma unroll
                for (int ni = 0; ni < 8; ++ni) {
                    acc[0][ni] = __builtin_amdgcn_mfma_f32_16x16x32_bf16(af0, bfr[ni], acc[0][ni], 0, 0, 0);
                    acc[1][ni] = __builtin_amdgcn_mfma_f32_16x16x32_bf16(af1, bfr[ni], acc[1][ni], 0, 0, 0);
                }
                __builtin_amdgcn_s_setprio(0);
                __builtin_amdgcn_s_barrier();
                __builtin_amdgcn_sched_barrier(0);

                // ======== sub-phase 3: kk=1, mi 2..3; tail vmcnt(0) ========
                {
                    int lc = 4 + quad;
                    af2 = *(bf16x8*)(&Acur[(wm * 64 + 32 + l16) * 64 + (lc ^ a_sw) * 8]);
                    af3 = *(bf16x8*)(&Acur[(wm * 64 + 48 + l16) * 64 + (lc ^ a_sw) * 8]);
                }
                __builtin_amdgcn_s_barrier();
                asm volatile("s_waitcnt lgkmcnt(0)" ::: "memory");
                __builtin_amdgcn_sched_barrier(0);
                __builtin_amdgcn_s_setprio(1);
                #pragma unroll
                for (int ni = 0; ni < 8; ++ni) {
                    acc[2][ni] = __builtin_amdgcn_mfma_f32_16x16x32_bf16(af2, bfr[ni], acc[2][ni], 0, 0, 0);
                    acc[3][ni] = __builtin_amdgcn_mfma_f32_16x16x32_bf16(af3, bfr[ni], acc[3][ni], 0, 0, 0);
                }
                __builtin_amdgcn_s_setprio(0);
                // staged loads (issued in sub-phase 0, ~3 sub-phases ago) have landed;
                // this wait+barrier validates next half-phase's buffers for everyone.
                asm volatile("s_waitcnt vmcnt(0)" ::: "memory");
                __builtin_amdgcn_s_barrier();
                __builtin_amdgcn_sched_barrier(0);
            }
        }
    }

    // epilogue: C/D layout col(spatial)=lane&15, row(co)=quad*4+reg
    int sp0 = wn * 128 + l16;
    #pragma unroll
    for (int mi = 0; mi < 4; ++mi) {
        #pragma unroll
        for (int r = 0; r < 4; ++r) {
            int co = wm * 64 + mi * 16 + quad * 4 + r;
            float b = bias[co];
            float* orow = out + (size_t)co * (HH * WW) + h * WW + sp0;
            #pragma unroll
            for (int ni = 0; ni < 8; ++ni)
                orow[ni * 16] = acc[mi][ni][r] + b;
        }
    }
}

extern "C" void kernel_launch(void* const* d_in, const int* in_sizes, int n_in,
                              void* d_out, int out_size, void* d_ws, size_t ws_size,
                              hipStream_t stream) {
    const float* x    = (const float*)d_in[0];   // [1,128,256,256]
    const float* w    = (const float*)d_in[1];   // [256,128,3,3]
    const float* bias = (const float*)d_in[2];   // [256]
    float* out        = (float*)d_out;           // [1,256,256,256]

    unsigned short* xb = (unsigned short*)d_ws;              // 258*258*128 bf16 = 17,040,384 B
    unsigned short* wr = xb + (size_t)HP * HP * CIN;         // 9*256*128 bf16  =    589,824 B

    prep_kernel<<<dim3(1024), dim3(256), 0, stream>>>(x, w, xb, wr);
    conv_mfma_kernel<<<dim3(256), dim3(512), 0, stream>>>(xb, wr, bias, out);
}

// Round 4
// 137.228 us; speedup vs baseline: 1.0844x; 1.0844x over previous
//
#include <hip/hip_runtime.h>
#include <hip/hip_bf16.h>

// Conv 3x3, C_IN=128, C_OUT=256, H=W=256, pad=1, stride=1, batch=1.
// R11: R9 skeleton + self-contained 2-sub-phase compute split.
//   R10 post-mortem: carrying bfr[8] across barrier pairs + sched_barrier fences
//   caused scratch spill (WRITE 65.5->88.4 MB, FETCH 11->37 MB) and 144 barrier
//   pairs of overhead -> 71 us. R9's monolith (24 reads then 64 MFMA per barrier
//   pair) serializes the LDS pipe (~17.3 us total) against the MFMA pipe
//   (~18.6 us) -> 57 us.
//   Now: per half-phase (khw, ci-half), two SELF-CONTAINED sub-phases
//   {12 ds_read_b128 -> 32 MFMA} (kk=0 / kk=1), each ending with raw s_barrier +
//   sched_barrier(0). No operand register crosses a barrier -> no spill. Per-CU
//   stage costs: reads 1152 cyc vs MFMA 1242 cyc -> balanced 2-stage pipeline.
//   Staging identical to R9: A half-plane dbuf + counted vmcnt(4) prefetch;
//   B full padded row (66 KB) staged at kh bounds (exposed, ~3x small cost).
//   LDS 131.6 KB, 1 block/CU, 8 waves of 64co x 128sp.

typedef short bf16x8 __attribute__((ext_vector_type(8)));    // 8 bf16 = 4 VGPRs
typedef float f32x4 __attribute__((ext_vector_type(4)));
typedef unsigned short u16x4 __attribute__((ext_vector_type(4)));
typedef unsigned short u16x8 __attribute__((ext_vector_type(8)));

#define CIN   128
#define COUT  256
#define HH    256
#define WW    256
#define HP    258                 // padded
#define ROWP  (HP * CIN)          // padded row stride in elems = 33024

static __device__ __forceinline__ unsigned short f2bf(float v) {
    __hip_bfloat16 b = __float2bfloat16(v);
    return *reinterpret_cast<unsigned short*>(&b);
}

static __device__ __forceinline__ void gload_lds16(const unsigned short* g, unsigned short* l) {
    __builtin_amdgcn_global_load_lds(
        (const __attribute__((address_space(1))) unsigned int*)g,
        (__attribute__((address_space(3))) unsigned int*)l, 16, 0, 0);
}

// ---------------- dispatch 1: fused prepass (edge zero + wreorder + xpose) -----------
// grid: 1024 blocks x 256 threads -- unchanged, verified
__global__ __launch_bounds__(256) void prep_kernel(const float* __restrict__ x,
                                                   const float* __restrict__ w,
                                                   unsigned short* __restrict__ xb,
                                                   unsigned short* __restrict__ wr) {
    int bid = blockIdx.x;
    int t   = threadIdx.x;

    // (a) edge zeroing: blocks 0..64 cover the 16448 vec8 border tasks
    if (bid < 65) {
        int i = bid * 256 + t;
        if (i < 16448) {
            u16x8 z = {0, 0, 0, 0, 0, 0, 0, 0};
            int off;
            if (i < 8256) {
                int r   = (i >= 4128) ? 1 : 0;
                int rem = i - r * 4128;
                off = (r * 257) * ROWP + rem * 8;
            } else {
                int j   = i - 8256;           // 0..8191
                int col = j >> 12;            // 0 or 1
                int rem = j & 4095;
                int hp  = (rem >> 4) + 1;     // 1..256
                int c8  = rem & 15;
                off = hp * ROWP + (col * 257) * CIN + c8 * 8;
            }
            *(u16x8*)(&xb[off]) = z;
        }
    }

    // (b) weight reorder: blocks 0..127, one thread per (co,ci), coalesced
    if (bid < 128) {
        int p = bid * 256 + t;    // 0..32767 = co*128+ci
        const float* src = w + p * 9;
        #pragma unroll
        for (int khw = 0; khw < 9; ++khw)
            wr[khw * (COUT * CIN) + p] = f2bf(src[khw]);
    }

    // (c) xpose: NCHW fp32 -> padded NHWC bf16, one 64-w tile per block
    int h  = bid >> 2;
    int w0 = (bid & 3) * 64;
    __shared__ unsigned short tile[CIN * 72];   // [ci][w], w padded 64->72

    int wq  = t & 15;          // 16 * float4 = 64 w
    int cib = t >> 4;          // 16 ci per pass
    for (int c0 = 0; c0 < CIN; c0 += 16) {
        int ci = c0 + cib;
        float4 v = *(const float4*)(x + ci * (HH * WW) + h * WW + w0 + wq * 4);
        u16x4 p;
        p.x = f2bf(v.x); p.y = f2bf(v.y); p.z = f2bf(v.z); p.w = f2bf(v.w);
        *(u16x4*)(&tile[ci * 72 + wq * 4]) = p;
    }
    __syncthreads();

    for (int it = 0; it < 4; ++it) {
        int idx = it * 256 + t;       // 0..1023
        int ww_ = idx & 63;           // varies within wave (conflict-free LDS reads)
        int c8  = idx >> 6;           // 0..15, wave-uniform
        u16x8 o;
        #pragma unroll
        for (int j = 0; j < 8; ++j)
            o[j] = tile[(c8 * 8 + j) * 72 + ww_];
        int dst = ((h + 1) * HP + (w0 + ww_ + 1)) * CIN + c8 * 8;
        *(u16x8*)(&xb[dst]) = o;
    }
}

// ---------------- dispatch 2: implicit-GEMM MFMA conv, 2-sub-phase pipeline ----------
// block tile 256co x 256sp (one output row h), 8 waves of 64co x 128sp, 1 block/CU.
// 18 half-phases i: khw = i>>1, ci-half = i&1. A half-plane (256x64, 32 KB) double-
// buffered, prefetched one half-phase ahead, validated by vmcnt(4) (counted: only
// the newest 4 loads -- the prefetch -- may remain in flight).
// Bw[col 0..257][ci 0..127]: 16B chunk c of col at slot c^(col&15) (16-slot XOR).
// Ah[p][row 0..255][ci 0..63]: 16B local chunk c of row at slot c^(row&7).
__global__ __launch_bounds__(512, 2) void conv_mfma_kernel(const unsigned short* __restrict__ xb,
                                                           const unsigned short* __restrict__ wr,
                                                           const float* __restrict__ bias,
                                                           float* __restrict__ out) {
    __shared__ unsigned short Bw[258 * 128];       // 66048 B
    __shared__ unsigned short Ah[2][256 * 64];     // 2 x 32768 B ; total LDS 131584 B

    // XCD-chunked bijective swizzle: 256 blocks, 8 XCDs -> 32 consecutive rows per XCD.
    int bid = blockIdx.x;
    int h   = (bid & 7) * 32 + (bid >> 3);     // 0..255, one output row per block

    int t    = threadIdx.x;     // 0..511
    int lane = t & 63;
    int wave = t >> 6;
    int wm   = wave >> 1;       // co quarter (0..3), 64 co each
    int wn   = wave & 1;        // spatial half (0/1), 128 sp each
    int quad = lane >> 4;
    int l16  = lane & 15;

    f32x4 acc[4][8];
    #pragma unroll
    for (int mi = 0; mi < 4; ++mi)
        #pragma unroll
        for (int ni = 0; ni < 8; ++ni)
            acc[mi][ni] = (f32x4){0.f, 0.f, 0.f, 0.f};

    // stage one 32 KB A half-plane (2048 segs of 16B, 4 per thread) into buffer
    auto stageA = [&](int idx) {
        int khw_  = idx >> 1;
        int half_ = idx & 1;
        const unsigned short* wsrc = wr + (size_t)khw_ * (COUT * CIN) + half_ * 64;
        unsigned short* dst = Ah[half_];
        #pragma unroll
        for (int it = 0; it < 4; ++it) {
            int seg = it * 512 + t;
            int r   = seg >> 3;
            int s   = seg & 7;
            int c   = s ^ (r & 7);
            gload_lds16(wsrc + r * CIN + c * 8, &dst[seg * 8]);
        }
    };

    // prologue: A half 0 into buffer 0 (4 loads/thread in flight)
    stageA(0);

    #pragma unroll 1
    for (int i = 0; i < 18; ++i) {
        int khw  = i >> 1;
        int half = i & 1;
        int kw   = khw % 3;

        // kh boundary: stage full B row (258 cols x 16 chunks = 4128+32 segs).
        // Bw's previous readers finished at iter i-1's trailing barrier.
        if ((i % 6) == 0) {
            const unsigned short* xrow = xb + (size_t)(h + i / 6) * ROWP;
            #pragma unroll
            for (int it = 0; it < 8; ++it) {
                int seg = it * 512 + t;
                int col = seg >> 4;
                int s   = seg & 15;
                int c   = s ^ (col & 15);
                gload_lds16(xrow + col * CIN + c * 8, &Bw[seg * 8]);
            }
            if (t < 32) {
                int seg = 4096 + t;
                int col = seg >> 4;
                int s   = seg & 15;
                int c   = s ^ (col & 15);
                gload_lds16(xrow + col * CIN + c * 8, &Bw[seg * 8]);
            }
        }

        // prefetch next A half (dummy wrap at i=17 keeps the vmcnt count uniform;
        // target buffer's last reader was compute(i-1), protected by its barrier)
        stageA((i + 1) % 18);

        // counted wait: everything except the 4 newest (the A-prefetch) has landed
        asm volatile("s_waitcnt vmcnt(4)" ::: "memory");
        __builtin_amdgcn_s_barrier();
        __builtin_amdgcn_sched_barrier(0);

        const unsigned short* Acur = Ah[half];
        int a_sw = l16 & 7;

        // ======== sub-phase 0: kk=0 (lc=quad), 12 reads -> 32 MFMA ========
        {
            int lc = quad;
            int cg = half * 8 + lc;
            bf16x8 af[4], bfr[8];
            #pragma unroll
            for (int mi = 0; mi < 4; ++mi) {
                int row = wm * 64 + mi * 16 + l16;
                af[mi] = *(bf16x8*)(&Acur[row * 64 + (lc ^ a_sw) * 8]);
            }
            #pragma unroll
            for (int ni = 0; ni < 8; ++ni) {
                int col = wn * 128 + ni * 16 + l16 + kw;
                bfr[ni] = *(bf16x8*)(&Bw[col * 128 + (cg ^ (col & 15)) * 8]);
            }
            __builtin_amdgcn_s_setprio(1);
            #pragma unroll
            for (int mi = 0; mi < 4; ++mi)
                #pragma unroll
                for (int ni = 0; ni < 8; ++ni)
                    acc[mi][ni] = __builtin_amdgcn_mfma_f32_16x16x32_bf16(
                        af[mi], bfr[ni], acc[mi][ni], 0, 0, 0);
            __builtin_amdgcn_s_setprio(0);
        }
        __builtin_amdgcn_s_barrier();
        __builtin_amdgcn_sched_barrier(0);

        // ======== sub-phase 1: kk=1 (lc=4+quad), 12 reads -> 32 MFMA ========
        {
            int lc = 4 + quad;
            int cg = half * 8 + lc;
            bf16x8 af[4], bfr[8];
            #pragma unroll
            for (int mi = 0; mi < 4; ++mi) {
                int row = wm * 64 + mi * 16 + l16;
                af[mi] = *(bf16x8*)(&Acur[row * 64 + (lc ^ a_sw) * 8]);
            }
            #pragma unroll
            for (int ni = 0; ni < 8; ++ni) {
                int col = wn * 128 + ni * 16 + l16 + kw;
                bfr[ni] = *(bf16x8*)(&Bw[col * 128 + (cg ^ (col & 15)) * 8]);
            }
            __builtin_amdgcn_s_setprio(1);
            #pragma unroll
            for (int mi = 0; mi < 4; ++mi)
                #pragma unroll
                for (int ni = 0; ni < 8; ++ni)
                    acc[mi][ni] = __builtin_amdgcn_mfma_f32_16x16x32_bf16(
                        af[mi], bfr[ni], acc[mi][ni], 0, 0, 0);
            __builtin_amdgcn_s_setprio(0);
        }
        // trailing barrier: all this half-phase's LDS reads are consumed (compiler
        // waits lgkm before each MFMA use) -> next iter may overwrite buffers.
        __builtin_amdgcn_s_barrier();
        __builtin_amdgcn_sched_barrier(0);
    }

    // epilogue: C/D layout col(spatial)=lane&15, row(co)=quad*4+reg
    int sp0 = wn * 128 + l16;
    #pragma unroll
    for (int mi = 0; mi < 4; ++mi) {
        #pragma unroll
        for (int r = 0; r < 4; ++r) {
            int co = wm * 64 + mi * 16 + quad * 4 + r;
            float b = bias[co];
            float* orow = out + (size_t)co * (HH * WW) + h * WW + sp0;
            #pragma unroll
            for (int ni = 0; ni < 8; ++ni)
                orow[ni * 16] = acc[mi][ni][r] + b;
        }
    }
}

extern "C" void kernel_launch(void* const* d_in, const int* in_sizes, int n_in,
                              void* d_out, int out_size, void* d_ws, size_t ws_size,
                              hipStream_t stream) {
    const float* x    = (const float*)d_in[0];   // [1,128,256,256]
    const float* w    = (const float*)d_in[1];   // [256,128,3,3]
    const float* bias = (const float*)d_in[2];   // [256]
    float* out        = (float*)d_out;           // [1,256,256,256]

    unsigned short* xb = (unsigned short*)d_ws;              // 258*258*128 bf16 = 17,040,384 B
    unsigned short* wr = xb + (size_t)HP * HP * CIN;         // 9*256*128 bf16  =    589,824 B

    prep_kernel<<<dim3(1024), dim3(256), 0, stream>>>(x, w, xb, wr);
    conv_mfma_kernel<<<dim3(256), dim3(512), 0, stream>>>(xb, wr, bias, out);
}

// Round 5
// 136.867 us; speedup vs baseline: 1.0873x; 1.0026x over previous
//
#include <hip/hip_runtime.h>
#include <hip/hip_bf16.h>

// Conv 3x3, C_IN=128, C_OUT=256, H=W=256, pad=1, stride=1, batch=1.
// R12: conv-specific kw register-reuse via DPP lane-rotates.
//   R11 post-mortem: LDS fragment reads (3456 b128/CU = 41.5 kcyc) are co-equal
//   with MFMA (44.7 kcyc); barrier lockstep serializes them -> ~51 us plateau
//   across 4 structures. b128 granularity makes reads/FLOP invariant to tile and
//   MFMA shape -- only CONV structure breaks it: B fragments for kw=1,2 are the
//   kw=0 fragments shifted by +1/+2 lanes (col = base + l16 + kw).
//   Now: read B once per K32-chunk (8 frags + 1 halo), derive kw=1,2 in-register:
//   DPP row_ror:15 (lane+1) / row_ror:14 (lane+2) within 16-lane rows, lanes 14/15
//   patched from the next fragment via cndmask. Reads 432 -> 252 b128/wave
//   (24.2 kcyc/CU < MFMA 44.7 kcyc); rotate cost rides the idle VALU pipe.
//   Loop: 6 iters of (kh, ci-half): stage 3 A half-planes (kw=0,1,2; 96 KB) +
//   B ci-half row (33 KB) single-buffered -> vmcnt(0)+barrier -> barrier-free
//   compute (2 chunks x 8 ni x 12 MFMA) -> barrier. 12 barriers total.
//   LDS 131.3 KB, 1 block/CU, 8 waves of 64co x 128sp. Swizzles/epilogue/prep
//   identical to verified R10/R11 patterns.

typedef short bf16x8 __attribute__((ext_vector_type(8)));    // 8 bf16 = 4 VGPRs
typedef float f32x4 __attribute__((ext_vector_type(4)));
typedef int   i32x4 __attribute__((ext_vector_type(4)));
typedef unsigned short u16x4 __attribute__((ext_vector_type(4)));
typedef unsigned short u16x8 __attribute__((ext_vector_type(8)));

#define CIN   128
#define COUT  256
#define HH    256
#define WW    256
#define HP    258                 // padded
#define ROWP  (HP * CIN)          // padded row stride in elems = 33024

static __device__ __forceinline__ unsigned short f2bf(float v) {
    __hip_bfloat16 b = __float2bfloat16(v);
    return *reinterpret_cast<unsigned short*>(&b);
}

static __device__ __forceinline__ void gload_lds16(const unsigned short* g, unsigned short* l) {
    __builtin_amdgcn_global_load_lds(
        (const __attribute__((address_space(1))) unsigned int*)g,
        (__attribute__((address_space(3))) unsigned int*)l, 16, 0, 0);
}

// DPP rotate within each 16-lane row: row_ror:N -> dst lane i <- src lane (i-N) mod 16.
// ror:15 == lane i <- lane i+1 ; ror:14 == lane i <- lane i+2.
template<int CTRL>
static __device__ __forceinline__ bf16x8 rotf(bf16x8 a) {
    i32x4 ai = __builtin_bit_cast(i32x4, a);
    i32x4 r;
    #pragma unroll
    for (int j = 0; j < 4; ++j)
        r[j] = __builtin_amdgcn_mov_dpp(ai[j], CTRL, 0xF, 0xF, true);
    return __builtin_bit_cast(bf16x8, r);
}
#define ROR_P1 0x12F   // row_ror:15  (shift +1 lane)
#define ROR_P2 0x12E   // row_ror:14  (shift +2 lanes)

// ---------------- dispatch 1: fused prepass (edge zero + wreorder + xpose) -----------
// grid: 1024 blocks x 256 threads -- unchanged, verified
__global__ __launch_bounds__(256) void prep_kernel(const float* __restrict__ x,
                                                   const float* __restrict__ w,
                                                   unsigned short* __restrict__ xb,
                                                   unsigned short* __restrict__ wr) {
    int bid = blockIdx.x;
    int t   = threadIdx.x;

    // (a) edge zeroing: blocks 0..64 cover the 16448 vec8 border tasks
    if (bid < 65) {
        int i = bid * 256 + t;
        if (i < 16448) {
            u16x8 z = {0, 0, 0, 0, 0, 0, 0, 0};
            int off;
            if (i < 8256) {
                int r   = (i >= 4128) ? 1 : 0;
                int rem = i - r * 4128;
                off = (r * 257) * ROWP + rem * 8;
            } else {
                int j   = i - 8256;           // 0..8191
                int col = j >> 12;            // 0 or 1
                int rem = j & 4095;
                int hp  = (rem >> 4) + 1;     // 1..256
                int c8  = rem & 15;
                off = hp * ROWP + (col * 257) * CIN + c8 * 8;
            }
            *(u16x8*)(&xb[off]) = z;
        }
    }

    // (b) weight reorder: blocks 0..127, one thread per (co,ci), coalesced
    if (bid < 128) {
        int p = bid * 256 + t;    // 0..32767 = co*128+ci
        const float* src = w + p * 9;
        #pragma unroll
        for (int khw = 0; khw < 9; ++khw)
            wr[khw * (COUT * CIN) + p] = f2bf(src[khw]);
    }

    // (c) xpose: NCHW fp32 -> padded NHWC bf16, one 64-w tile per block
    int h  = bid >> 2;
    int w0 = (bid & 3) * 64;
    __shared__ unsigned short tile[CIN * 72];   // [ci][w], w padded 64->72

    int wq  = t & 15;          // 16 * float4 = 64 w
    int cib = t >> 4;          // 16 ci per pass
    for (int c0 = 0; c0 < CIN; c0 += 16) {
        int ci = c0 + cib;
        float4 v = *(const float4*)(x + ci * (HH * WW) + h * WW + w0 + wq * 4);
        u16x4 p;
        p.x = f2bf(v.x); p.y = f2bf(v.y); p.z = f2bf(v.z); p.w = f2bf(v.w);
        *(u16x4*)(&tile[ci * 72 + wq * 4]) = p;
    }
    __syncthreads();

    for (int it = 0; it < 4; ++it) {
        int idx = it * 256 + t;       // 0..1023
        int ww_ = idx & 63;           // varies within wave (conflict-free LDS reads)
        int c8  = idx >> 6;           // 0..15, wave-uniform
        u16x8 o;
        #pragma unroll
        for (int j = 0; j < 8; ++j)
            o[j] = tile[(c8 * 8 + j) * 72 + ww_];
        int dst = ((h + 1) * HP + (w0 + ww_ + 1)) * CIN + c8 * 8;
        *(u16x8*)(&xb[dst]) = o;
    }
}

// ---------------- dispatch 2: implicit-GEMM MFMA conv, kw-rotate reuse ---------------
// block tile 256co x 256sp (one output row h), 8 waves of 64co x 128sp, 1 block/CU.
// Per iter (kh, ci-half): A half-planes for kw=0,1,2 (each [256 rows][64 ci], chunk c
// of row at slot c^(row&7)) + B ci-half row ([258 cols][64 ci], chunk c of col at slot
// c^(col&7)). Compute: per K32-chunk, af[3kw][4mi] (12 reads) then stream bfr[ni]
// (9 reads incl. halo); kw=1/2 operands derived by DPP rotate + next-frag patch.
__global__ __launch_bounds__(512, 2) void conv_mfma_kernel(const unsigned short* __restrict__ xb,
                                                           const unsigned short* __restrict__ wr,
                                                           const float* __restrict__ bias,
                                                           float* __restrict__ out) {
    __shared__ unsigned short A0[256 * 64];    // 32768 B  (kw=0)
    __shared__ unsigned short A1[256 * 64];    // 32768 B  (kw=1)
    __shared__ unsigned short A2[256 * 64];    // 32768 B  (kw=2)
    __shared__ unsigned short Bs[258 * 64];    // 33024 B  ; total 131328 B

    // XCD-chunked bijective swizzle: 256 blocks, 8 XCDs -> 32 consecutive rows per XCD.
    int bid = blockIdx.x;
    int h   = (bid & 7) * 32 + (bid >> 3);     // 0..255, one output row per block

    int t    = threadIdx.x;     // 0..511
    int lane = t & 63;
    int wave = t >> 6;
    int wm   = wave >> 1;       // co quarter (0..3), 64 co each
    int wn   = wave & 1;        // spatial half (0/1), 128 sp each
    int quad = lane >> 4;
    int l16  = lane & 15;

    f32x4 acc[4][8];
    #pragma unroll
    for (int mi = 0; mi < 4; ++mi)
        #pragma unroll
        for (int ni = 0; ni < 8; ++ni)
            acc[mi][ni] = (f32x4){0.f, 0.f, 0.f, 0.f};

    unsigned short* const Ap[3] = {A0, A1, A2};

    #pragma unroll 1
    for (int i = 0; i < 6; ++i) {
        int kh     = i >> 1;
        int cihalf = i & 1;

        // ---- stage (single-buffered; prev readers done at prev trailing barrier) ----
        // A: 3 half-planes x 2048 segs of 16B (12 segs/thread)
        #pragma unroll
        for (int p = 0; p < 3; ++p) {
            const unsigned short* wsrc = wr + (size_t)(kh * 3 + p) * (COUT * CIN) + cihalf * 64;
            unsigned short* dst = Ap[p];
            #pragma unroll
            for (int it = 0; it < 4; ++it) {
                int seg = it * 512 + t;
                int r   = seg >> 3;
                int s   = seg & 7;
                int c   = s ^ (r & 7);
                gload_lds16(wsrc + r * CIN + c * 8, &dst[seg * 8]);
            }
        }
        // B: cols 0..257 of padded row h+kh, this ci-half: 2064 segs (4/thread + tail)
        {
            const unsigned short* xrow = xb + (size_t)(h + kh) * ROWP + cihalf * 64;
            #pragma unroll
            for (int it = 0; it < 4; ++it) {
                int seg = it * 512 + t;
                int col = seg >> 3;
                int s   = seg & 7;
                int c   = s ^ (col & 7);
                gload_lds16(xrow + col * CIN + c * 8, &Bs[col * 64 + s * 8]);
            }
            if (t < 16) {
                int seg = 2048 + t;           // cols 256, 257
                int col = seg >> 3;
                int s   = seg & 7;
                int c   = s ^ (col & 7);
                gload_lds16(xrow + col * CIN + c * 8, &Bs[col * 64 + s * 8]);
            }
        }
        asm volatile("s_waitcnt vmcnt(0)" ::: "memory");
        __builtin_amdgcn_s_barrier();
        __builtin_amdgcn_sched_barrier(0);

        // ---- compute: barrier-free region, 2 K32-chunks ----
        #pragma unroll
        for (int kk = 0; kk < 2; ++kk) {
            int ck  = kk * 4 + quad;              // storage chunk 0..7 within ci-half
            int asl = (ck ^ (l16 & 7)) * 8;       // A slot offset (row&7 == l16&7)

            bf16x8 af0[4], af1[4], af2[4];
            #pragma unroll
            for (int mi = 0; mi < 4; ++mi) {
                int ro = (wm * 64 + mi * 16 + l16) * 64;
                af0[mi] = *(const bf16x8*)(&A0[ro + asl]);
                af1[mi] = *(const bf16x8*)(&A1[ro + asl]);
                af2[mi] = *(const bf16x8*)(&A2[ro + asl]);
            }

            // B fragment reader (halo cols >257 clamp to 257; those lanes unused)
            auto rdB = [&](int ni_) -> bf16x8 {
                int col = wn * 128 + ni_ * 16 + l16;
                if (col > 257) col = 257;
                return *(const bf16x8*)(&Bs[col * 64 + ((ck ^ (col & 7)) * 8)]);
            };

            bf16x8 cur = rdB(0);
            #pragma unroll
            for (int ni = 0; ni < 8; ++ni) {
                bf16x8 nxt = rdB(ni + 1);
                // kw=1 operand: col base+l16+1 ; lane15 takes next frag's lane0
                bf16x8 r1c = rotf<ROR_P1>(cur), r1n = rotf<ROR_P1>(nxt);
                bf16x8 s1  = (l16 == 15) ? r1n : r1c;
                // kw=2 operand: col base+l16+2 ; lanes14,15 take next frag's lanes0,1
                bf16x8 r2c = rotf<ROR_P2>(cur), r2n = rotf<ROR_P2>(nxt);
                bf16x8 s2  = (l16 >= 14) ? r2n : r2c;

                __builtin_amdgcn_s_setprio(1);
                #pragma unroll
                for (int mi = 0; mi < 4; ++mi)
                    acc[mi][ni] = __builtin_amdgcn_mfma_f32_16x16x32_bf16(
                        af0[mi], cur, acc[mi][ni], 0, 0, 0);
                #pragma unroll
                for (int mi = 0; mi < 4; ++mi)
                    acc[mi][ni] = __builtin_amdgcn_mfma_f32_16x16x32_bf16(
                        af1[mi], s1, acc[mi][ni], 0, 0, 0);
                #pragma unroll
                for (int mi = 0; mi < 4; ++mi)
                    acc[mi][ni] = __builtin_amdgcn_mfma_f32_16x16x32_bf16(
                        af2[mi], s2, acc[mi][ni], 0, 0, 0);
                __builtin_amdgcn_s_setprio(0);
                cur = nxt;
            }
        }
        // trailing barrier: all LDS reads consumed (compiler lgkm-waits before MFMA use)
        __builtin_amdgcn_s_barrier();
        __builtin_amdgcn_sched_barrier(0);
    }

    // epilogue: C/D layout col(spatial)=lane&15, row(co)=quad*4+reg
    int sp0 = wn * 128 + l16;
    #pragma unroll
    for (int mi = 0; mi < 4; ++mi) {
        #pragma unroll
        for (int r = 0; r < 4; ++r) {
            int co = wm * 64 + mi * 16 + quad * 4 + r;
            float b = bias[co];
            float* orow = out + (size_t)co * (HH * WW) + h * WW + sp0;
            #pragma unroll
            for (int ni = 0; ni < 8; ++ni)
                orow[ni * 16] = acc[mi][ni][r] + b;
        }
    }
}

extern "C" void kernel_launch(void* const* d_in, const int* in_sizes, int n_in,
                              void* d_out, int out_size, void* d_ws, size_t ws_size,
                              hipStream_t stream) {
    const float* x    = (const float*)d_in[0];   // [1,128,256,256]
    const float* w    = (const float*)d_in[1];   // [256,128,3,3]
    const float* bias = (const float*)d_in[2];   // [256]
    float* out        = (float*)d_out;           // [1,256,256,256]

    unsigned short* xb = (unsigned short*)d_ws;              // 258*258*128 bf16 = 17,040,384 B
    unsigned short* wr = xb + (size_t)HP * HP * CIN;         // 9*256*128 bf16  =    589,824 B

    prep_kernel<<<dim3(1024), dim3(256), 0, stream>>>(x, w, xb, wr);
    conv_mfma_kernel<<<dim3(256), dim3(512), 0, stream>>>(xb, wr, bias, out);
}